// Round 15
// baseline (94.628 us; speedup 1.0000x reference)
//
#include <hip/hip_runtime.h>
#include <hip/hip_fp16.h>
#include <math.h>

#define LRES 2048
#define NB 8
#define KSEL 64
#define EMBD 16
#define NAA 20
#define NBIN 128
#define BINSCALE 1.28f          // bin = trunc(d2 * 1.28), d2 < 100 -> bin < 128
#define BINW 0.78125f           // 100/128, upper edge = (T+1)*BINW

// packed-f16 dot product with f32 accumulate: d = a.x*b.x + a.y*b.y + c
static __device__ __forceinline__ float fdot2u(unsigned a, unsigned b, float c) {
#if __has_builtin(__builtin_amdgcn_fdot2)
    typedef _Float16 h2f __attribute__((ext_vector_type(2)));
    union { unsigned u; h2f h; } ua, ub;
    ua.u = a; ub.u = b;
    return __builtin_amdgcn_fdot2(ua.h, ub.h, c, false);
#else
    float d;
    asm("v_dot2_f32_f16 %0, %1, %2, %3" : "=v"(d) : "v"(a), "v"(b), "v"(c));
    return d;
#endif
}

static __device__ __forceinline__ unsigned hadd2u(unsigned a, unsigned b) {
    __half2 ha = *(__half2*)&a, hb = *(__half2*)&b;
    __half2 r = __hadd2(ha, hb);
    return *(unsigned*)&r;
}

// pack two f32 into one u32 of f16 halves (lo=a, hi=b), round-toward-zero.
// r14 fix: let the builtin's own return type drive the declaration (clang on
// gfx950 returns __fp16 ext_vector(2), not _Float16 ext_vector(2)).
static __device__ __forceinline__ unsigned pk16(float a, float b) {
#if __has_builtin(__builtin_amdgcn_cvt_pkrtz)
    __typeof__(__builtin_amdgcn_cvt_pkrtz(0.0f, 0.0f)) r =
        __builtin_amdgcn_cvt_pkrtz(a, b);
    union { __typeof__(r) h; unsigned u; } cv;
    cv.h = r;
    return cv.u;
#else
    __half2 r = __floats2half2_rn(a, b);
    return *(unsigned*)&r;
#endif
}

// ---- DPP wave64 inclusive scan (VALU-only) ----
template <int CTRL, int RM>
static __device__ __forceinline__ unsigned dpp_u(unsigned v) {
    return (unsigned)__builtin_amdgcn_update_dpp(0, (int)v, CTRL, RM, 0xf, true);
}
static __device__ __forceinline__ unsigned wave_iscan_u(unsigned s) {
    s += dpp_u<0x111, 0xf>(s);   // row_shr:1
    s += dpp_u<0x112, 0xf>(s);   // row_shr:2
    s += dpp_u<0x114, 0xf>(s);   // row_shr:4
    s += dpp_u<0x118, 0xf>(s);   // row_shr:8
    s += dpp_u<0x142, 0xa>(s);   // row_bcast:15 -> rows 1,3
    s += dpp_u<0x143, 0xc>(s);   // row_bcast:31 -> rows 2,3
    return s;
}
static __device__ __forceinline__ float wave_iscan_f(float a) {
    a += __uint_as_float(dpp_u<0x111, 0xf>(__float_as_uint(a)));
    a += __uint_as_float(dpp_u<0x112, 0xf>(__float_as_uint(a)));
    a += __uint_as_float(dpp_u<0x114, 0xf>(__float_as_uint(a)));
    a += __uint_as_float(dpp_u<0x118, 0xf>(__float_as_uint(a)));
    a += __uint_as_float(dpp_u<0x142, 0xa>(__float_as_uint(a)));
    a += __uint_as_float(dpp_u<0x143, 0xc>(__float_as_uint(a)));
    return a;
}

#define LDS_FENCE() asm volatile("s_waitcnt lgkmcnt(0)" ::: "memory")

// TWO rows per wave (iA, iA+1): one ds_read_b128 feeds distance math for both
// centers -> per-row pass-1 LDS reads halve (the binding pipe per r13's
// confirmed model). d2 stored as packed f16 pairs (lo=A, hi=B) so register
// footprint is unchanged. Hist bins from pre-pack f32 (as before); capture
// compares f16 bits vs smallest-f16 >= bin edge (monotone <=> f32 compare).
// Both rows' energies fold into one accumulator (only batch sums matter).
// 1024 blocks x 512 thr; LDS ~25 KB; 8 waves/block -> 4 blocks/CU (wave-cap).
__global__ __launch_bounds__(512, 8) void repel_kernel(
    const float* __restrict__ R,
    const int* __restrict__ seq,
    const float* __restrict__ emb,
    const float* __restrict__ wv,
    const float* __restrict__ bias,
    float* __restrict__ partial)
{
    const int tid  = threadIdx.x;
    const int w    = tid >> 6;
    const int lane = tid & 63;
    const int k    = blockIdx.x;              // 1024 blocks, 128 per batch
    const int b    = k >> 7;
    const int iA   = ((k & 127) << 4) + (w << 1);   // rows iA, iA+1
    const int iB   = iA + 1;

    __shared__ uint2    Pl[LRES];             // 16 KB packed points
    __shared__ unsigned hist[16][NBIN];       // 8 KB (2 hists per wave)
    __shared__ float    rho_tab[NAA];         // 80 B
    __shared__ unsigned shT[16];
    __shared__ float    shS[8];

    const float* __restrict__ Rb = R + b * (LRES * 3);
    const int*   __restrict__ Sb = seq + b * LRES;

    // ---- stage 0: rho table (20 dots of length 16) ----
    if (tid < NAA) {
        float x = bias[0];
#pragma unroll
        for (int d = 0; d < EMBD; ++d) x += emb[tid * EMBD + d] * wv[d];
        rho_tab[tid] = 1.6f + 1.2f / (1.0f + __expf(-x));
    }
    __syncthreads();

    // ---- stage 1: pack 4 points/thread into LDS ----
#pragma unroll
    for (int q = 0; q < 4; ++q) {
        int p = (q << 9) + tid;
        float x = Rb[p * 3 + 0], y = Rb[p * 3 + 1], z = Rb[p * 3 + 2];
        float rho = rho_tab[Sb[p]];
        __half2 h0 = __floats2half2_rn(x, y);
        __half2 h1 = __floats2half2_rn(z, rho);
        Pl[p] = make_uint2(*(unsigned*)&h0, *(unsigned*)&h1);
    }

    // zero own wave's two histograms (2 bins/lane each) + default T = NBIN-1
    *(uint2*)&hist[(w << 1) + 0][lane << 1] = make_uint2(0u, 0u);
    *(uint2*)&hist[(w << 1) + 1][lane << 1] = make_uint2(0u, 0u);
    if (lane == 0) { shT[(w << 1)] = NBIN - 1; shT[(w << 1) + 1] = NBIN - 1; }
    __syncthreads();

    // centers A and B: negated half2 (x,y) and masked+negated half2 (z, 0)
    const uint2 cA = Pl[iA];
    const unsigned ncxyA = cA.x ^ 0x80008000u;
    const unsigned nczvA = (cA.y & 0x0000FFFFu) ^ 0x00008000u;
    const float rho_iA = __high2float(*(__half2*)&cA.y);
    const uint2 cB = Pl[iB];
    const unsigned ncxyB = cB.x ^ 0x80008000u;
    const unsigned nczvB = (cB.y & 0x0000FFFFu) ^ 0x00008000u;
    const float rho_iB = __high2float(*(__half2*)&cB.y);

    // shared exclusion window for both rows: union [iA-2, iB+2] spans <=2 t-blocks
    const int s_iA = __builtin_amdgcn_readfirstlane(iA);
    const int tlo = ((s_iA - 2 > 0) ? (s_iA - 2) : 0) >> 7;
    const int thi = ((s_iA + 3 < LRES - 1) ? (s_iA + 3) : (LRES - 1)) >> 7;

    const unsigned lane2 = (unsigned)lane << 1;

    // ---- pass 1: one read serves both rows; hist from f32; store packed f16 ----
    const uint4* __restrict__ P4 = (const uint4*)Pl;
    unsigned d2h[32];
#pragma unroll
    for (int t = 0; t < 16; ++t) {
        uint4 u = P4[(t << 6) + lane];               // ds_read_b128, conflict-free
        int j0 = (t << 7) + (int)lane2;
        unsigned dxy, dz;
        dxy = hadd2u(u.x, ncxyA); dz = hadd2u(u.y, nczvA) & 0x0000FFFFu;
        float d0A = fdot2u(dxy, dxy, fdot2u(dz, dz, 0.0f));
        dxy = hadd2u(u.x, ncxyB); dz = hadd2u(u.y, nczvB) & 0x0000FFFFu;
        float d0B = fdot2u(dxy, dxy, fdot2u(dz, dz, 0.0f));
        dxy = hadd2u(u.z, ncxyA); dz = hadd2u(u.w, nczvA) & 0x0000FFFFu;
        float d1A = fdot2u(dxy, dxy, fdot2u(dz, dz, 0.0f));
        dxy = hadd2u(u.z, ncxyB); dz = hadd2u(u.w, nczvB) & 0x0000FFFFu;
        float d1B = fdot2u(dxy, dxy, fdot2u(dz, dz, 0.0f));
        if (t == tlo || t == thi) {                  // wave-uniform branch
            int e;
            e = j0 - iA;     e = (e < 0) ? -e : e; if (e <= 2) d0A = 1.0e9f;
            e = j0 - iB;     e = (e < 0) ? -e : e; if (e <= 2) d0B = 1.0e9f;
            e = j0 + 1 - iA; e = (e < 0) ? -e : e; if (e <= 2) d1A = 1.0e9f;
            e = j0 + 1 - iB; e = (e < 0) ? -e : e; if (e <= 2) d1B = 1.0e9f;
        }
        if (d0A < 100.0f) atomicAdd(&hist[(w << 1) + 0][(unsigned)(d0A * BINSCALE)], 1u);
        if (d0B < 100.0f) atomicAdd(&hist[(w << 1) + 1][(unsigned)(d0B * BINSCALE)], 1u);
        if (d1A < 100.0f) atomicAdd(&hist[(w << 1) + 0][(unsigned)(d1A * BINSCALE)], 1u);
        if (d1B < 100.0f) atomicAdd(&hist[(w << 1) + 1][(unsigned)(d1B * BINSCALE)], 1u);
        d2h[2 * t]     = pk16(d0A, d0B);
        d2h[2 * t + 1] = pk16(d1A, d1B);
    }
    LDS_FENCE();   // own wave's atomics visible (hists wave-private)

    // ---- scans: two DPP wave64 inclusive scans; crossing lanes set T ----
    uint2 hvA = *(const uint2*)&hist[(w << 1) + 0][lane << 1];
    uint2 hvB = *(const uint2*)&hist[(w << 1) + 1][lane << 1];
    unsigned pA = hvA.x + hvA.y, pB = hvB.x + hvB.y;
    unsigned sA = wave_iscan_u(pA), sB = wave_iscan_u(pB);
    unsigned eA = sA - pA, eB = sB - pB;
    if (sA >= KSEL && eA < KSEL) {
        unsigned sub = (eA + hvA.x >= KSEL) ? 0u : 1u;
        shT[(w << 1) + 0] = (lane << 1) + sub;
    }
    if (sB >= KSEL && eB < KSEL) {
        unsigned sub = (eB + hvB.x >= KSEL) ? 0u : 1u;
        shT[(w << 1) + 1] = (lane << 1) + sub;
    }
    LDS_FENCE();
    const unsigned TA = shT[(w << 1) + 0];
    const unsigned TB = shT[(w << 1) + 1];

    // f16-bit thresholds: smallest f16 >= (T+1)*BINW; compare on positive-f16
    // bits <=> f32(d2h) < edge. Excluded pairs hold huge f16 -> never pass.
    float EAf = (float)(TA + 1) * BINW;
    __half hA = __float2half_rz(EAf);
    unsigned thA = (unsigned)__half_as_ushort(hA) + ((__half2float(hA) < EAf) ? 1u : 0u);
    float EBf = (float)(TB + 1) * BINW;
    __half hB = __float2half_rz(EBf);
    unsigned thB = (unsigned)__half_as_ushort(hB) + ((__half2float(hB) < EBf) ? 1u : 0u);

    // ---- capture: per-lane selection bitmasks (pure VALU, no LDS) ----
    unsigned selA = 0u, selB = 0u;
#pragma unroll
    for (int m = 0; m < 32; ++m) {
        unsigned v = d2h[m];
        selA |= ((v & 0xFFFFu) < thA) ? (1u << m) : 0u;
        selB |= ((v >> 16)     < thB) ? (1u << m) : 0u;
    }

    // ---- eval both rows into one accumulator (only batch sums matter) ----
    float acc = 0.0f;
#pragma unroll 1
    for (int rsel = 0; rsel < 2; ++rsel) {
        unsigned msk      = rsel ? selB : selA;
        const unsigned nx = rsel ? ncxyB : ncxyA;
        const unsigned nz = rsel ? nczvB : nczvA;
        const float    ri = rsel ? rho_iB : rho_iA;
        while (msk) {
            unsigned m = (unsigned)__builtin_ctz(msk);
            msk &= msk - 1u;
            unsigned j = ((((m >> 1) << 7) | (m & 1)) | lane2);
            uint2 pj = Pl[j];
            unsigned dxy = hadd2u(pj.x, nx);
            unsigned dz  = hadd2u(pj.y, nz) & 0x0000FFFFu;
            float d2 = fdot2u(dxy, dxy, fdot2u(dz, dz, 0.0f));
            float r  = __fsqrt_rn(fmaxf(d2, 1e-12f));
            float rho_j = __high2float(*(__half2*)&pj.y);
            float x = (ri + rho_j - r) * (1.0f / 0.3f);
            float sp = fmaxf(x, 0.0f) + __logf(1.0f + __expf(-fabsf(x)));
            float t = fminf(fmaxf((r - 8.0f) * 0.5f, 0.0f), 1.0f);
            float sw = 1.0f - t * t * (3.0f - 2.0f * t);
            acc += 10.0f * sp * sw;
        }
    }

    // ---- DPP scan reduce (total lands in lane 63) -> block combine -> one store ----
    float atot = wave_iscan_f(acc);
    float wsum = __uint_as_float(__builtin_amdgcn_readlane(__float_as_uint(atot), 63));
    if (lane == 0) shS[w] = wsum;
    __syncthreads();
    if (tid == 0) {
        float v = 0.0f;
#pragma unroll
        for (int q = 0; q < 8; ++q) v += shS[q];
        partial[k] = v;
    }
}

// out[b] = sum of 128 per-block partials (blocks 128b .. 128b+127)
__global__ void reduce_kernel(const float* __restrict__ partial, float* __restrict__ out) {
    __shared__ float sh[4];
    const int b = blockIdx.x;
    const int tid = threadIdx.x;
    float acc = (tid < 128) ? partial[(b << 7) + tid] : 0.0f;
#pragma unroll
    for (int o = 32; o > 0; o >>= 1) acc += __shfl_down(acc, o, 64);
    if ((tid & 63) == 0) sh[tid >> 6] = acc;
    __syncthreads();
    if (tid == 0) out[b] = sh[0] + sh[1] + sh[2] + sh[3];
}

extern "C" void kernel_launch(void* const* d_in, const int* in_sizes, int n_in,
                              void* d_out, int out_size, void* d_ws, size_t ws_size,
                              hipStream_t stream) {
    const float* R    = (const float*)d_in[0];   // (8, 2048, 3) f32
    const int*   seq  = (const int*)d_in[1];     // (8, 2048) int
    const float* emb  = (const float*)d_in[2];   // (20, 16) f32
    const float* w    = (const float*)d_in[3];   // (1, 16) f32
    const float* bias = (const float*)d_in[4];   // (1,) f32
    float* out = (float*)d_out;                  // (8,) f32

    float* partial = (float*)d_ws;               // 4 KB (1024 block partials)

    repel_kernel<<<NB * LRES / 16, 512, 0, stream>>>(R, seq, emb, w, bias, partial);
    reduce_kernel<<<NB, 256, 0, stream>>>(partial, out);
}

// Round 16
// 81.348 us; speedup vs baseline: 1.1633x; 1.1633x over previous
//
#include <hip/hip_runtime.h>
#include <hip/hip_fp16.h>
#include <math.h>

#define LRES 2048
#define NB 8
#define KSEL 64
#define EMBD 16
#define NAA 20
#define NBIN 128
#define BINSCALE 1.28f          // bin = trunc(d2 * 1.28), d2 < 100 -> bin < 128
#define BINW 0.78125f           // 100/128, upper edge = (T+1)*BINW

// packed-f16 dot product with f32 accumulate: d = a.x*b.x + a.y*b.y + c
static __device__ __forceinline__ float fdot2u(unsigned a, unsigned b, float c) {
#if __has_builtin(__builtin_amdgcn_fdot2)
    typedef _Float16 h2f __attribute__((ext_vector_type(2)));
    union { unsigned u; h2f h; } ua, ub;
    ua.u = a; ub.u = b;
    return __builtin_amdgcn_fdot2(ua.h, ub.h, c, false);
#else
    float d;
    asm("v_dot2_f32_f16 %0, %1, %2, %3" : "=v"(d) : "v"(a), "v"(b), "v"(c));
    return d;
#endif
}

static __device__ __forceinline__ unsigned hadd2u(unsigned a, unsigned b) {
    __half2 ha = *(__half2*)&a, hb = *(__half2*)&b;
    __half2 r = __hadd2(ha, hb);
    return *(unsigned*)&r;
}

// ---- DPP wave64 inclusive scan (VALU-only) ----
template <int CTRL, int RM>
static __device__ __forceinline__ unsigned dpp_u(unsigned v) {
    return (unsigned)__builtin_amdgcn_update_dpp(0, (int)v, CTRL, RM, 0xf, true);
}
static __device__ __forceinline__ unsigned wave_iscan_u(unsigned s) {
    s += dpp_u<0x111, 0xf>(s);   // row_shr:1
    s += dpp_u<0x112, 0xf>(s);   // row_shr:2
    s += dpp_u<0x114, 0xf>(s);   // row_shr:4
    s += dpp_u<0x118, 0xf>(s);   // row_shr:8
    s += dpp_u<0x142, 0xa>(s);   // row_bcast:15 -> rows 1,3
    s += dpp_u<0x143, 0xc>(s);   // row_bcast:31 -> rows 2,3
    return s;
}
static __device__ __forceinline__ float wave_iscan_f(float a) {
    a += __uint_as_float(dpp_u<0x111, 0xf>(__float_as_uint(a)));
    a += __uint_as_float(dpp_u<0x112, 0xf>(__float_as_uint(a)));
    a += __uint_as_float(dpp_u<0x114, 0xf>(__float_as_uint(a)));
    a += __uint_as_float(dpp_u<0x118, 0xf>(__float_as_uint(a)));
    a += __uint_as_float(dpp_u<0x142, 0xa>(__float_as_uint(a)));
    a += __uint_as_float(dpp_u<0x143, 0xc>(__float_as_uint(a)));
    return a;
}

#define LDS_FENCE() asm volatile("s_waitcnt lgkmcnt(0)" ::: "memory")

// Round-13 kernel verbatim — session best (81.62 us). One row per wave,
// 8 waves/block; DPP scan (r7 win) + per-lane bitmask capture (r13 win).
__global__ __launch_bounds__(512, 8) void repel_kernel(
    const float* __restrict__ R,
    const int* __restrict__ seq,
    const float* __restrict__ emb,
    const float* __restrict__ wv,
    const float* __restrict__ bias,
    float* __restrict__ partial)
{
    const int tid  = threadIdx.x;
    const int w    = tid >> 6;
    const int lane = tid & 63;
    const int row  = blockIdx.x * 8 + w;
    const int b    = row >> 11;
    const int i    = row & (LRES - 1);

    __shared__ uint2    Pl[LRES];              // 16 KB packed points
    __shared__ unsigned hist[8][NBIN];         // 4 KB
    __shared__ float    rho_tab[NAA];          // 80 B
    __shared__ unsigned shT[8];
    __shared__ float    shS[8];

    const float* __restrict__ Rb = R + b * (LRES * 3);
    const int*   __restrict__ Sb = seq + b * LRES;

    // ---- stage 0: rho table (20 dots of length 16) ----
    if (tid < NAA) {
        float x = bias[0];
#pragma unroll
        for (int d = 0; d < EMBD; ++d) x += emb[tid * EMBD + d] * wv[d];
        rho_tab[tid] = 1.6f + 1.2f / (1.0f + __expf(-x));
    }
    __syncthreads();

    // ---- stage 1: pack 4 points/thread into LDS ----
#pragma unroll
    for (int q = 0; q < 4; ++q) {
        int p = (q << 9) + tid;
        float x = Rb[p * 3 + 0], y = Rb[p * 3 + 1], z = Rb[p * 3 + 2];
        float rho = rho_tab[Sb[p]];
        __half2 h0 = __floats2half2_rn(x, y);
        __half2 h1 = __floats2half2_rn(z, rho);
        Pl[p] = make_uint2(*(unsigned*)&h0, *(unsigned*)&h1);
    }

    // zero own wave's histogram (2 bins/lane) + default T = NBIN-1
    *(uint2*)&hist[w][lane << 1] = make_uint2(0u, 0u);
    if (lane == 0) shT[w] = NBIN - 1;
    __syncthreads();

    // center: negated half2 (x,y) and masked+negated half2 (z, 0); rho_i as f32
    const uint2 ci = Pl[i];
    const unsigned ncxy = ci.x ^ 0x80008000u;                 // (-cx, -cy) packed
    const unsigned nczv = (ci.y & 0x0000FFFFu) ^ 0x00008000u; // (-cz, +0) packed
    const float rho_i = __high2float(*(__half2*)&ci.y);

    // scalar exclusion window: i is wave-uniform -> SGPR; t covers 128 j's
    const int s_i = __builtin_amdgcn_readfirstlane(i);
    const int tlo = ((s_i - 2 > 0) ? (s_i - 2) : 0) >> 7;
    const int thi = ((s_i + 2 < LRES - 1) ? (s_i + 2) : (LRES - 1)) >> 7;

    const unsigned lane2 = (unsigned)lane << 1;
    const unsigned exbits = __float_as_uint(1.0e9f);          // > any threshold

    // ---- pass 1: distances from LDS (lane owns 32 j's) + fused per-wave histogram ----
    const uint4* __restrict__ P4 = (const uint4*)Pl;
    unsigned d2u[32];
#pragma unroll
    for (int t = 0; t < 16; ++t) {
        uint4 u = P4[(t << 6) + lane];               // ds_read_b128, conflict-free
        int j0 = (t << 7) + (int)lane2;
        unsigned dxyA = hadd2u(u.x, ncxy);
        unsigned dzA  = hadd2u(u.y, nczv) & 0x0000FFFFu;
        float d2a = fdot2u(dxyA, dxyA, fdot2u(dzA, dzA, 0.0f));
        unsigned dxyB = hadd2u(u.z, ncxy);
        unsigned dzB  = hadd2u(u.w, nczv) & 0x0000FFFFu;
        float d2b = fdot2u(dxyB, dxyB, fdot2u(dzB, dzB, 0.0f));
        unsigned dua = __float_as_uint(d2a);
        unsigned dub = __float_as_uint(d2b);
        if (t == tlo || t == thi) {                  // wave-uniform branch
            int e0 = j0 - i;     e0 = (e0 < 0) ? -e0 : e0;
            int e1 = j0 + 1 - i; e1 = (e1 < 0) ? -e1 : e1;
            if (e0 <= 2) dua = exbits;
            if (e1 <= 2) dub = exbits;
        }
        d2u[2 * t]     = dua;
        d2u[2 * t + 1] = dub;
        if (dua <= 0x42C7FFFFu)                      // d2 < 100.0
            atomicAdd(&hist[w][(unsigned)(d2a * BINSCALE)], 1u);
        if (dub <= 0x42C7FFFFu)
            atomicAdd(&hist[w][(unsigned)(d2b * BINSCALE)], 1u);
    }
    LDS_FENCE();   // own wave's atomics visible (hist[w] wave-private)

    // ---- scan: lane holds 2 bins; DPP wave64 inclusive scan; crossing lane sets T ----
    uint2 hv = *(const uint2*)&hist[w][lane << 1];
    unsigned p = hv.x + hv.y;
    unsigned s = wave_iscan_u(p);
    unsigned e0s = s - p;
    if (s >= KSEL && e0s < KSEL) {                   // unique crossing lane (if total >= 64)
        unsigned sub = (e0s + hv.x >= KSEL) ? 0u : 1u;
        shT[w] = (lane << 1) + sub;                  // whole boundary bin selected
    }
    LDS_FENCE();
    const unsigned T   = shT[w];
    const unsigned tkb = __float_as_uint((float)(T + 1) * BINW);

    // ---- capture: per-lane selection bitmask (pure VALU, no LDS) ----
    unsigned selmask = 0u;
#pragma unroll
    for (int m = 0; m < 32; ++m)
        selmask |= (d2u[m] < tkb) ? (1u << m) : 0u;

    // ---- eval: walk set bits; j reconstructed from m; d2 recomputed bit-identically ----
    float acc = 0.0f;
    unsigned msk = selmask;
    while (msk) {
        unsigned m = (unsigned)__builtin_ctz(msk);
        msk &= msk - 1u;
        unsigned j = ((((m >> 1) << 7) | (m & 1)) | lane2);
        uint2 pj = Pl[j];
        unsigned dxy = hadd2u(pj.x, ncxy);
        unsigned dz  = hadd2u(pj.y, nczv) & 0x0000FFFFu;
        float d2 = fdot2u(dxy, dxy, fdot2u(dz, dz, 0.0f));
        float r  = __fsqrt_rn(fmaxf(d2, 1e-12f));
        float rho_j = __high2float(*(__half2*)&pj.y);
        float x = (rho_i + rho_j - r) * (1.0f / 0.3f);
        float sp = fmaxf(x, 0.0f) + __logf(1.0f + __expf(-fabsf(x)));
        float t = fminf(fmaxf((r - 8.0f) * 0.5f, 0.0f), 1.0f);
        float sw = 1.0f - t * t * (3.0f - 2.0f * t);
        acc += 10.0f * sp * sw;
    }

    // ---- DPP scan reduce (total lands in lane 63) -> block combine -> one store ----
    float atot = wave_iscan_f(acc);
    float wsum = __uint_as_float(__builtin_amdgcn_readlane(__float_as_uint(atot), 63));
    if (lane == 0) shS[w] = wsum;
    __syncthreads();
    if (tid == 0) {
        float v = 0.0f;
#pragma unroll
        for (int q = 0; q < 8; ++q) v += shS[q];
        partial[blockIdx.x] = v;
    }
}

// out[b] = sum of 256 per-block partials (blocks 256b .. 256b+255)
__global__ void reduce_kernel(const float* __restrict__ partial, float* __restrict__ out) {
    __shared__ float sh[4];
    const int b = blockIdx.x;
    const int tid = threadIdx.x;
    float acc = partial[(b << 8) + tid];
#pragma unroll
    for (int o = 32; o > 0; o >>= 1) acc += __shfl_down(acc, o, 64);
    if ((tid & 63) == 0) sh[tid >> 6] = acc;
    __syncthreads();
    if (tid == 0) out[b] = sh[0] + sh[1] + sh[2] + sh[3];
}

extern "C" void kernel_launch(void* const* d_in, const int* in_sizes, int n_in,
                              void* d_out, int out_size, void* d_ws, size_t ws_size,
                              hipStream_t stream) {
    const float* R    = (const float*)d_in[0];   // (8, 2048, 3) f32
    const int*   seq  = (const int*)d_in[1];     // (8, 2048) int
    const float* emb  = (const float*)d_in[2];   // (20, 16) f32
    const float* w    = (const float*)d_in[3];   // (1, 16) f32
    const float* bias = (const float*)d_in[4];   // (1,) f32
    float* out = (float*)d_out;                  // (8,) f32

    float* partial = (float*)d_ws;               // 8 KB (2048 block partials)

    repel_kernel<<<NB * LRES / 8, 512, 0, stream>>>(R, seq, emb, w, bias, partial);
    reduce_kernel<<<NB, 256, 0, stream>>>(partial, out);
}